// Round 2
// baseline (1347.431 us; speedup 1.0000x reference)
//
#include <hip/hip_runtime.h>

// Fused GNN edge scorer: concat(x[src],x[dst],e,nf[src],nf[dst],ef) [E,214]
//   -> relu(@W1.T+b1) [E,128] -> relu(@W2.T+b2) [E,32] -> @W3.T+b3 [E,2]
// fp32 VALU (no fp32 MFMA on CDNA4).
//
// Path A (needs ws >= N*128*2*4 B): algebraic split of layer 1.
//   Psrc[n] = x[n]@W1[:,0:64].T + nf[n]@W1[:,192:202].T   (per-node, E/N=32 reuse)
//   Pdst[n] = x[n]@W1[:,64:128].T + nf[n]@W1[:,202:212].T
//   edge:  h1 = relu(e@W1[:,128:192].T + ef-rank2 + Psrc[src] + Pdst[dst] + b1)
// Path B: fully fused baseline (gathers all 214 features per edge).

#define ETILE 32
constexpr int CONCAT = 214;

// ---------------------------------------------------------------------------
// Path A kernel 1: per-node precompute of Psrc/Pdst  [N,128] each
// ---------------------------------------------------------------------------
__global__ __launch_bounds__(256, 2)
void node_precompute(const float* __restrict__ xg, const float* __restrict__ nfg,
                     const float* __restrict__ W1,
                     float* __restrict__ Ps, float* __restrict__ Pd, int N)
{
    // LDS: data [96][32] (x 64 + nf 10, zero-padded to 96) + two W chunk bufs
    __shared__ float smem[96 * 32 + 2 * 32 * 132];   // 11520 floats = 46080 B
    float (*data_l)[32]  = reinterpret_cast<float(*)[32]>(smem);          // [96][32]
    float (*wsb)[132]    = reinterpret_cast<float(*)[132]>(smem + 3072);  // [32][132]
    float (*wdb)[132]    = reinterpret_cast<float(*)[132]>(smem + 7296);  // [32][132]

    const int t = threadIdx.x;
    const long nBase = (long)blockIdx.x * 32;

    // gather x(64)+nf(10) -> data_l[kappa][node]
    {
        const int ni = t & 31;
        const int g  = t >> 5;       // 0..7
        const long Ng = nBase + ni;
        if (Ng < N) {
            const float* xp = xg + Ng * 64;
            const int k8 = g * 8;
            #pragma unroll
            for (int i = 0; i < 8; ++i) data_l[k8 + i][ni] = xp[k8 + i];
            if (g == 0) {
                const float* np = nfg + Ng * 10;
                #pragma unroll
                for (int i = 0; i < 10; ++i) data_l[64 + i][ni] = np[i];
                #pragma unroll
                for (int k = 74; k < 96; ++k) data_l[k][ni] = 0.f;
            }
        } else if (g == 0) {
            for (int k = 0; k < 96; ++k) data_l[k][ni] = 0.f;
        }
    }

    const int jt = t & 31, ng = t >> 5;
    const int j0 = jt * 4, n0 = ng * 4;     // thread tile: 4 nodes x 4 j
    const int jW  = t >> 1;                 // staging row of W1 (0..127)
    const int kk0 = (t & 1) * 16;

    float accS[4][4], accD[4][4];
    #pragma unroll
    for (int a = 0; a < 4; ++a)
        #pragma unroll
        for (int b = 0; b < 4; ++b) { accS[a][b] = 0.f; accD[a][b] = 0.f; }

    const float* wrow = W1 + (long)jW * CONCAT;
    for (int kc = 0; kc < 3; ++kc) {
        __syncthreads();
        #pragma unroll
        for (int ii = 0; ii < 16; ++ii) {
            const int kap = kc * 32 + kk0 + ii;
            float vs = 0.f, vd = 0.f;
            if (kap < 74) {
                const int cs = (kap < 64) ? kap        : (192 + kap - 64);
                const int cd = (kap < 64) ? (64 + kap) : (202 + kap - 64);
                vs = wrow[cs];
                vd = wrow[cd];
            }
            wsb[kk0 + ii][jW] = vs;
            wdb[kk0 + ii][jW] = vd;
        }
        __syncthreads();
        const int kb = kc * 32;
        #pragma unroll 4
        for (int kk = 0; kk < 32; ++kk) {
            const float4 dv = *(const float4*)&data_l[kb + kk][n0];
            const float4 sv = *(const float4*)&wsb[kk][j0];
            const float4 wv = *(const float4*)&wdb[kk][j0];
            const float dd[4] = {dv.x, dv.y, dv.z, dv.w};
            const float ss[4] = {sv.x, sv.y, sv.z, sv.w};
            const float ww[4] = {wv.x, wv.y, wv.z, wv.w};
            #pragma unroll
            for (int nn = 0; nn < 4; ++nn)
                #pragma unroll
                for (int jj = 0; jj < 4; ++jj) {
                    accS[nn][jj] = fmaf(dd[nn], ss[jj], accS[nn][jj]);
                    accD[nn][jj] = fmaf(dd[nn], ww[jj], accD[nn][jj]);
                }
        }
    }

    #pragma unroll
    for (int nn = 0; nn < 4; ++nn) {
        const long Ng = nBase + n0 + nn;
        if (Ng < N) {
            *(float4*)&Ps[Ng * 128 + j0] =
                make_float4(accS[nn][0], accS[nn][1], accS[nn][2], accS[nn][3]);
            *(float4*)&Pd[Ng * 128 + j0] =
                make_float4(accD[nn][0], accD[nn][1], accD[nn][2], accD[nn][3]);
        }
    }
}

// ---------------------------------------------------------------------------
// Path A kernel 2: edge kernel with decomposed layer 1 (K=64 e-GEMM only)
// ---------------------------------------------------------------------------
__global__ __launch_bounds__(256, 3)
void edge_mlp_decomp(
    const float* __restrict__ eg, const float* __restrict__ efg,
    const int* __restrict__ src, const int* __restrict__ dst,
    const float* __restrict__ Ps, const float* __restrict__ Pd,
    const float* __restrict__ W1, const float* __restrict__ b1,
    const float* __restrict__ W2, const float* __restrict__ b2,
    const float* __restrict__ W3, const float* __restrict__ b3,
    float* __restrict__ out, int E)
{
    // 12032 floats = 48128 B -> 3 blocks/CU (144 KB of 160 KB)
    __shared__ float smem[12032];
    float (*data_l)[ETILE] = reinterpret_cast<float(*)[ETILE]>(smem);       // [64][32] e-tile k-major
    float (*w1buf)[132]    = reinterpret_cast<float(*)[132]>(smem + 2048);  // [32][132]
    float (*h1)[36]        = reinterpret_cast<float(*)[36]>(smem + 6272);   // [128][36]
    float (*h2)[36]        = reinterpret_cast<float(*)[36]>(smem + 10880);  // [32][36]
    float (*w2buf)[36]     = reinterpret_cast<float(*)[36]>(smem);          // [128][36] aliases data_l+w1buf
    __shared__ int   sidx[ETILE];
    __shared__ int   didx[ETILE];
    __shared__ float efl[2][ETILE];

    const int t = threadIdx.x;
    const long eBase = (long)blockIdx.x * ETILE;

    // ---------------- gather: e rows -> data_l[k][edge]; idx/ef -> LDS ------
    {
        const int ei = t & 31;
        const int g  = t >> 5;
        const long Eg = eBase + ei;
        if (Eg < E) {
            const float* ep = eg + Eg * 64;
            const int k8 = g * 8;
            const float4 a = *(const float4*)(ep + k8);
            const float4 b = *(const float4*)(ep + k8 + 4);
            const float tmp[8] = {a.x,a.y,a.z,a.w,b.x,b.y,b.z,b.w};
            #pragma unroll
            for (int i = 0; i < 8; ++i) data_l[k8 + i][ei] = tmp[i];
            if (g == 0) {
                sidx[ei] = src[Eg];
                didx[ei] = dst[Eg];
                efl[0][ei] = efg[Eg * 2 + 0];
                efl[1][ei] = efg[Eg * 2 + 1];
            }
        } else if (g == 0) {
            for (int k = 0; k < 64; ++k) data_l[k][ei] = 0.f;
            sidx[ei] = 0; didx[ei] = 0; efl[0][ei] = 0.f; efl[1][ei] = 0.f;
        }
    }

    // ---------------- layer 1: [32e x 128j] over k=64 (e block of W1) ------
    const int jt = t & 31, et = t >> 5;
    const int j0 = jt * 4, e0 = et * 4;
    const int jW  = t >> 1;
    const int kk0 = (t & 1) * 16;

    // rank-2 ef weights for this thread's 4 j's (cols 212,213)
    float w212[4], w213[4];
    #pragma unroll
    for (int jj = 0; jj < 4; ++jj) {
        w212[jj] = W1[(long)(j0 + jj) * CONCAT + 212];
        w213[jj] = W1[(long)(j0 + jj) * CONCAT + 213];
    }

    float acc[4][4];
    #pragma unroll
    for (int a = 0; a < 4; ++a)
        #pragma unroll
        for (int b = 0; b < 4; ++b) acc[a][b] = 0.f;

    const float* wrow = W1 + (long)jW * CONCAT + 128;   // e-column block
    float wreg[16];
    #pragma unroll
    for (int ii = 0; ii < 16; ++ii) wreg[ii] = wrow[kk0 + ii];   // chunk 0

    for (int kc = 0; kc < 2; ++kc) {
        __syncthreads();
        #pragma unroll
        for (int ii = 0; ii < 16; ++ii) w1buf[kk0 + ii][jW] = wreg[ii];
        if (kc == 0) {
            #pragma unroll
            for (int ii = 0; ii < 16; ++ii) wreg[ii] = wrow[32 + kk0 + ii];
        }
        __syncthreads();
        const int kb = kc * 32;
        #pragma unroll 4
        for (int kk = 0; kk < 32; ++kk) {
            const float4 dv = *(const float4*)&data_l[kb + kk][e0];
            const float4 wv = *(const float4*)&w1buf[kk][j0];
            const float dd[4] = {dv.x, dv.y, dv.z, dv.w};
            const float ww[4] = {wv.x, wv.y, wv.z, wv.w};
            #pragma unroll
            for (int ee = 0; ee < 4; ++ee)
                #pragma unroll
                for (int jj = 0; jj < 4; ++jj)
                    acc[ee][jj] = fmaf(dd[ee], ww[jj], acc[ee][jj]);
        }
    }

    // ---------------- epilogue: + Psrc[src] + Pdst[dst] + ef-rank2 + b1 ----
    float pacc[4][4];
    #pragma unroll
    for (int ee = 0; ee < 4; ++ee) {
        const int e_ = e0 + ee;
        const long Eg = eBase + e_;
        float pv[4] = {0.f, 0.f, 0.f, 0.f};
        if (Eg < E) {
            const float4 ps = *(const float4*)&Ps[(long)sidx[e_] * 128 + j0];
            const float4 pd = *(const float4*)&Pd[(long)didx[e_] * 128 + j0];
            const float ef0 = efl[0][e_], ef1 = efl[1][e_];
            pv[0] = ps.x + pd.x + ef0 * w212[0] + ef1 * w213[0];
            pv[1] = ps.y + pd.y + ef0 * w212[1] + ef1 * w213[1];
            pv[2] = ps.z + pd.z + ef0 * w212[2] + ef1 * w213[2];
            pv[3] = ps.w + pd.w + ef0 * w212[3] + ef1 * w213[3];
        }
        #pragma unroll
        for (int jj = 0; jj < 4; ++jj) pacc[ee][jj] = pv[jj];
    }
    {
        const float4 bv = *(const float4*)(b1 + j0);
        const float bb[4] = {bv.x, bv.y, bv.z, bv.w};
        #pragma unroll
        for (int jj = 0; jj < 4; ++jj) {
            float4 hv;
            hv.x = fmaxf(acc[0][jj] + pacc[0][jj] + bb[jj], 0.f);
            hv.y = fmaxf(acc[1][jj] + pacc[1][jj] + bb[jj], 0.f);
            hv.z = fmaxf(acc[2][jj] + pacc[2][jj] + bb[jj], 0.f);
            hv.w = fmaxf(acc[3][jj] + pacc[3][jj] + bb[jj], 0.f);
            *(float4*)&h1[j0 + jj][e0] = hv;
        }
    }
    __syncthreads();   // data_l/w1buf dead; h1 complete

    // ---------------- stage W2 transposed ----------------------------------
    for (int i = t; i < 32 * 128; i += 256) {
        const int k = i & 127, j2 = i >> 7;
        w2buf[k][j2] = W2[j2 * 128 + k];
    }
    __syncthreads();

    // ---------------- layer 2: [32e x 32j] over k=128 ----------------------
    {
        const int e2 = t & 31, jg = t >> 5;
        const int j2b = jg * 4;
        float a2[4] = {0.f, 0.f, 0.f, 0.f};
        #pragma unroll 8
        for (int k = 0; k < 128; ++k) {
            const float dv = h1[k][e2];
            const float4 wv = *(const float4*)&w2buf[k][j2b];
            a2[0] = fmaf(dv, wv.x, a2[0]);
            a2[1] = fmaf(dv, wv.y, a2[1]);
            a2[2] = fmaf(dv, wv.z, a2[2]);
            a2[3] = fmaf(dv, wv.w, a2[3]);
        }
        #pragma unroll
        for (int jj = 0; jj < 4; ++jj)
            h2[j2b + jj][e2] = fmaxf(a2[jj] + b2[j2b + jj], 0.f);
    }
    __syncthreads();

    // ---------------- layer 3: [32e x 2] over k=32 -------------------------
    if (t < 64) {
        const int e3 = t >> 1, c = t & 1;
        float a3 = b3[c];
        #pragma unroll
        for (int k = 0; k < 32; ++k) a3 = fmaf(h2[k][e3], W3[c * 32 + k], a3);
        const long Eo = eBase + e3;
        if (Eo < E) out[Eo * 2 + c] = a3;
    }
}

// ---------------------------------------------------------------------------
// Path B: fully fused baseline (fallback when ws is too small)
// ---------------------------------------------------------------------------
constexpr int NCH_B = 7;

__global__ __launch_bounds__(256, 2)
void fused_gnn_edge_mlp(
    const float* __restrict__ xg, const float* __restrict__ eg,
    const float* __restrict__ nfg, const float* __restrict__ efg,
    const int* __restrict__ src, const int* __restrict__ dst,
    const float* __restrict__ W1, const float* __restrict__ b1,
    const float* __restrict__ W2, const float* __restrict__ b2,
    const float* __restrict__ W3, const float* __restrict__ b3,
    float* __restrict__ out, int E)
{
    __shared__ float smem[16000];
    float (*data_l)[ETILE] = reinterpret_cast<float(*)[ETILE]>(smem);
    float (*w1buf)[132]    = reinterpret_cast<float(*)[132]>(smem + 7168);
    float (*h1)[36]        = reinterpret_cast<float(*)[36]>(smem + 11392);
    float (*w2buf)[36]     = reinterpret_cast<float(*)[36]>(smem);
    float (*h2)[36]        = reinterpret_cast<float(*)[36]>(smem + 4608);

    const int t = threadIdx.x;
    const long eBase = (long)blockIdx.x * ETILE;

    {
        const int ei = t & 31;
        const int g  = t >> 5;
        const long Eg = eBase + ei;
        if (Eg < E) {
            const int si = src[Eg], di = dst[Eg];
            const float* xs = xg + (long)si * 64;
            const float* xd = xg + (long)di * 64;
            const float* ep = eg + Eg * 64;
            const int k8 = g * 8;
            auto ld8_store = [&](const float* p, int kbase) {
                const float4 a = *(const float4*)(p);
                const float4 b = *(const float4*)(p + 4);
                const float tmp[8] = {a.x,a.y,a.z,a.w,b.x,b.y,b.z,b.w};
                #pragma unroll
                for (int i = 0; i < 8; ++i) data_l[kbase + i][ei] = tmp[i];
            };
            ld8_store(xs + k8, k8);
            ld8_store(xd + k8, 64 + k8);
            ld8_store(ep + k8, 128 + k8);
            if (g == 0) {
                const float* ns = nfg + (long)si * 10;
                const float* nd = nfg + (long)di * 10;
                #pragma unroll
                for (int i = 0; i < 10; ++i) data_l[192 + i][ei] = ns[i];
                #pragma unroll
                for (int i = 0; i < 10; ++i) data_l[202 + i][ei] = nd[i];
                data_l[212][ei] = efg[Eg * 2 + 0];
                data_l[213][ei] = efg[Eg * 2 + 1];
                #pragma unroll
                for (int k = 214; k < 224; ++k) data_l[k][ei] = 0.f;
            }
        } else if (g == 0) {
            for (int k = 0; k < 224; ++k) data_l[k][ei] = 0.f;
        }
    }

    const int jt = t & 31, et = t >> 5;
    const int j0 = jt * 4, e0 = et * 4;
    const int jW  = t >> 1;
    const int kk0 = (t & 1) * 16;

    float acc[4][4];
    #pragma unroll
    for (int a = 0; a < 4; ++a)
        #pragma unroll
        for (int b = 0; b < 4; ++b) acc[a][b] = 0.f;

    const float* wrow = W1 + (long)jW * CONCAT;
    float wreg[16];
    #pragma unroll
    for (int ii = 0; ii < 16; ++ii) wreg[ii] = wrow[kk0 + ii];

    for (int kc = 0; kc < NCH_B; ++kc) {
        __syncthreads();
        #pragma unroll
        for (int ii = 0; ii < 16; ++ii) w1buf[kk0 + ii][jW] = wreg[ii];
        if (kc + 1 < NCH_B) {
            const int Kb = (kc + 1) * 32 + kk0;
            #pragma unroll
            for (int ii = 0; ii < 16; ++ii) {
                const int K = Kb + ii;
                wreg[ii] = (K < CONCAT) ? wrow[K] : 0.f;
            }
        }
        __syncthreads();
        const int kb = kc * 32;
        #pragma unroll 4
        for (int kk = 0; kk < 32; ++kk) {
            const float4 dv = *(const float4*)&data_l[kb + kk][e0];
            const float4 wv = *(const float4*)&w1buf[kk][j0];
            const float dd[4] = {dv.x, dv.y, dv.z, dv.w};
            const float ww[4] = {wv.x, wv.y, wv.z, wv.w};
            #pragma unroll
            for (int ee = 0; ee < 4; ++ee)
                #pragma unroll
                for (int jj = 0; jj < 4; ++jj)
                    acc[ee][jj] = fmaf(dd[ee], ww[jj], acc[ee][jj]);
        }
    }
    {
        const float4 bv = *(const float4*)(b1 + j0);
        const float bb[4] = {bv.x, bv.y, bv.z, bv.w};
        #pragma unroll
        for (int jj = 0; jj < 4; ++jj) {
            float4 hv;
            hv.x = fmaxf(acc[0][jj] + bb[jj], 0.f);
            hv.y = fmaxf(acc[1][jj] + bb[jj], 0.f);
            hv.z = fmaxf(acc[2][jj] + bb[jj], 0.f);
            hv.w = fmaxf(acc[3][jj] + bb[jj], 0.f);
            *(float4*)&h1[j0 + jj][e0] = hv;
        }
    }
    __syncthreads();

    for (int i = t; i < 32 * 128; i += 256) {
        const int k = i & 127, j2 = i >> 7;
        w2buf[k][j2] = W2[j2 * 128 + k];
    }
    __syncthreads();

    {
        const int e2 = t & 31, jg = t >> 5;
        const int j2b = jg * 4;
        float a2[4] = {0.f, 0.f, 0.f, 0.f};
        #pragma unroll 8
        for (int k = 0; k < 128; ++k) {
            const float dv = h1[k][e2];
            const float4 wv = *(const float4*)&w2buf[k][j2b];
            a2[0] = fmaf(dv, wv.x, a2[0]);
            a2[1] = fmaf(dv, wv.y, a2[1]);
            a2[2] = fmaf(dv, wv.z, a2[2]);
            a2[3] = fmaf(dv, wv.w, a2[3]);
        }
        #pragma unroll
        for (int jj = 0; jj < 4; ++jj)
            h2[j2b + jj][e2] = fmaxf(a2[jj] + b2[j2b + jj], 0.f);
    }
    __syncthreads();

    if (t < 64) {
        const int e3 = t >> 1, c = t & 1;
        float a3 = b3[c];
        #pragma unroll
        for (int k = 0; k < 32; ++k) a3 = fmaf(h2[k][e3], W3[c * 32 + k], a3);
        const long Eo = eBase + e3;
        if (Eo < E) out[Eo * 2 + c] = a3;
    }
}

extern "C" void kernel_launch(void* const* d_in, const int* in_sizes, int n_in,
                              void* d_out, int out_size, void* d_ws, size_t ws_size,
                              hipStream_t stream) {
    const float* xg  = (const float*)d_in[0];
    const float* eg  = (const float*)d_in[1];
    const float* nfg = (const float*)d_in[2];
    const float* efg = (const float*)d_in[3];
    const int*   src = (const int*)d_in[4];
    const int*   dst = (const int*)d_in[5];
    const float* W1  = (const float*)d_in[6];
    const float* b1  = (const float*)d_in[7];
    const float* W2  = (const float*)d_in[8];
    const float* b2  = (const float*)d_in[9];
    const float* W3  = (const float*)d_in[10];
    const float* b3  = (const float*)d_in[11];
    float* out = (float*)d_out;
    const int E = in_sizes[4];
    const int N = in_sizes[0] / 64;
    const int egrid = (E + ETILE - 1) / ETILE;

    const size_t need = (size_t)N * 128 * 2 * sizeof(float);   // Psrc + Pdst
    if (ws_size >= need) {
        float* Ps = (float*)d_ws;
        float* Pd = Ps + (size_t)N * 128;
        const int ngrid = (N + 31) / 32;
        node_precompute<<<ngrid, 256, 0, stream>>>(xg, nfg, W1, Ps, Pd, N);
        edge_mlp_decomp<<<egrid, 256, 0, stream>>>(eg, efg, src, dst, Ps, Pd,
                                                   W1, b1, W2, b2, W3, b3, out, E);
    } else {
        fused_gnn_edge_mlp<<<egrid, 256, 0, stream>>>(xg, eg, nfg, efg, src, dst,
                                                      W1, b1, W2, b2, W3, b3, out, E);
    }
}